// Round 8
// baseline (1730.655 us; speedup 1.0000x reference)
//
#include <hip/hip_runtime.h>

#define NUM_PL 50000
#define NUM_TR 100000
#define NUM_AR 10000
#define NN     160000          // NUM_PL + NUM_TR + NUM_AR
#define HID    64
#define FEAT   128
#define E_PLTR 2000000
#define E_TRAR 100000
#define E_TOT  4200000         // 2*E_PLTR + 2*E_TRAR
#define OFF_TR 50000
#define OFF_AR 150000
#define NBLK_SCAN 625          // NN / 256
#define FILL_CHUNKS 2048
#define FILL_CHUNK_SZ ((E_TOT + FILL_CHUNKS - 1) / FILL_CHUNKS)   // 2051

// edge id -> (src,dst) global node ids, matching the reference concatenation
__device__ __forceinline__ void edge_sd(
    int e, const int* __restrict__ pls, const int* __restrict__ pld,
    const int* __restrict__ tas, const int* __restrict__ tad, int& s, int& d) {
  if (e < E_PLTR)                   { s = pls[e];               d = pld[e] + OFF_TR; }
  else if (e < 2 * E_PLTR)          { int i = e - E_PLTR;
                                      s = pld[i] + OFF_TR;      d = pls[i]; }
  else if (e < 2 * E_PLTR + E_TRAR) { int i = e - 2 * E_PLTR;
                                      s = tas[i] + OFF_TR;      d = tad[i] + OFF_AR; }
  else                              { int i = e - 2 * E_PLTR - E_TRAR;
                                      s = tad[i] + OFF_AR;      d = tas[i] + OFF_TR; }
}

// dst-range bucket, boundaries chosen to equalize edge counts (~525k each)
__device__ __forceinline__ int dst_bucket(int d) {
  if (d < 50000) return d / 12500;
  if (d < 150000) return 4 + (d - 50000) / 25000;
  return 7;
}

// ---------------------------------------------------------------------------
// x[pl] = playlist_emb + type_emb[0];  x[ar] = artist_emb + type_emb[2]
// ---------------------------------------------------------------------------
__global__ __launch_bounds__(256) void k_init_emb(
    const float* __restrict__ pl_emb, const float* __restrict__ ar_emb,
    const float* __restrict__ type_emb, float* __restrict__ x) {
  int tid = blockIdx.x * 256 + threadIdx.x;
  int f = tid & (HID - 1);
  if (tid < NUM_PL * HID) {
    x[tid] = pl_emb[tid] + type_emb[f];
  } else {
    int idx = tid - NUM_PL * HID;
    if (idx < NUM_AR * HID)
      x[OFF_AR * HID + idx] = ar_emb[idx] + type_emb[2 * HID + f];
  }
}

// ---------------------------------------------------------------------------
// x[tr] = track_x @ W^T + b + type_emb[1]   (wave: 8 rows, lane = out feat)
// ---------------------------------------------------------------------------
__global__ __launch_bounds__(256) void k_track_lin(
    const float* __restrict__ tx, const float* __restrict__ W,
    const float* __restrict__ b, const float* __restrict__ type_emb,
    float* __restrict__ x) {
  __shared__ float WS[FEAT * HID];   // WS[k*64 + j] = W[j*128 + k]
  __shared__ float bs[HID];
  int t = threadIdx.x;
  for (int idx = t; idx < HID * FEAT; idx += 256) {
    int j = idx >> 7, k = idx & (FEAT - 1);
    WS[k * HID + j] = W[idx];
  }
  if (t < HID) bs[t] = b[t] + type_emb[HID + t];
  __syncthreads();

  int j  = t & 63;
  int wv = __builtin_amdgcn_readfirstlane(t >> 6);
  int row0 = blockIdx.x * 32 + wv * 8;
  const float* xr = tx + (size_t)row0 * FEAT;

  float acc[8] = {0.f, 0.f, 0.f, 0.f, 0.f, 0.f, 0.f, 0.f};
#pragma unroll 4
  for (int k = 0; k < FEAT; ++k) {
    float w = WS[k * HID + j];
#pragma unroll
    for (int r = 0; r < 8; ++r)
      acc[r] += xr[r * FEAT + k] * w;
  }
#pragma unroll
  for (int r = 0; r < 8; ++r)
    x[(OFF_TR + row0 + r) * HID + j] = acc[r] + bs[j];
}

// ---------------------------------------------------------------------------
// CSR build: int degree count
// ---------------------------------------------------------------------------
__global__ __launch_bounds__(256) void k_deg_int(
    const int* __restrict__ pls, const int* __restrict__ pld,
    const int* __restrict__ tas, const int* __restrict__ tad,
    int* __restrict__ degi) {
  int e = blockIdx.x * 256 + threadIdx.x;
  if (e >= E_TOT) return;
  int s, d;
  edge_sd(e, pls, pld, tas, tad, s, d);
  atomicAdd(&degi[d], 1);
}

// ---------------------------------------------------------------------------
// scan1: per-block (256) exclusive scan of degi -> rowptr, block total -> bsum
// ---------------------------------------------------------------------------
__global__ __launch_bounds__(256) void k_scan1(
    const int* __restrict__ degi, int* __restrict__ rowptr,
    int* __restrict__ bsum) {
  __shared__ int s[256];
  int t = threadIdx.x;
  int i = blockIdx.x * 256 + t;
  int val = degi[i];
  s[t] = val;
  __syncthreads();
  int incl = val;
#pragma unroll
  for (int off = 1; off < 256; off <<= 1) {
    int add = (t >= off) ? s[t - off] : 0;
    __syncthreads();
    incl += add;
    s[t] = incl;
    __syncthreads();
  }
  rowptr[i] = incl - val;               // exclusive within block
  if (t == 255) bsum[blockIdx.x] = incl;
}

// ---------------------------------------------------------------------------
// scan2: single block (1024 threads) exclusive scan of the 625 block sums
// ---------------------------------------------------------------------------
__global__ __launch_bounds__(1024) void k_scan2(int* __restrict__ bsum) {
  __shared__ int s[1024];
  int t = threadIdx.x;
  int val = (t < NBLK_SCAN) ? bsum[t] : 0;
  s[t] = val;
  __syncthreads();
  int incl = val;
#pragma unroll
  for (int off = 1; off < 1024; off <<= 1) {
    int add = (t >= off) ? s[t - off] : 0;
    __syncthreads();
    incl += add;
    s[t] = incl;
    __syncthreads();
  }
  if (t < NBLK_SCAN) bsum[t] = incl - val;  // exclusive
}

// ---------------------------------------------------------------------------
// scan3: rowptr[i] += bsum[block]; cursor[i] = rowptr[i]; rowptr[NN]=E_TOT
// ---------------------------------------------------------------------------
__global__ __launch_bounds__(256) void k_scan3(
    int* __restrict__ rowptr, const int* __restrict__ bsum,
    int* __restrict__ cursor) {
  int i = blockIdx.x * 256 + threadIdx.x;
  int v = rowptr[i] + bsum[blockIdx.x];
  rowptr[i] = v;
  cursor[i] = v;
  if (i == 0) rowptr[NN] = E_TOT;
}

// ---------------------------------------------------------------------------
// fill: col[cursor[d]++] = s, bucketed by dst range (R3 version, verified)
// ---------------------------------------------------------------------------
__global__ __launch_bounds__(256) void k_fill(
    const int* __restrict__ pls, const int* __restrict__ pld,
    const int* __restrict__ tas, const int* __restrict__ tad,
    int* __restrict__ cursor, int* __restrict__ col) {
  int bucket = blockIdx.x & 7;
  int chunk  = blockIdx.x >> 3;
  int e0 = chunk * FILL_CHUNK_SZ;
  int e1 = e0 + FILL_CHUNK_SZ;
  if (e1 > E_TOT) e1 = E_TOT;
  for (int e = e0 + threadIdx.x; e < e1; e += 256) {
    int s, d;
    edge_sd(e, pls, pld, tas, tad, s, d);
    if (dst_bucket(d) == bucket) {
      int pos = atomicAdd(&cursor[d], 1);
      col[pos] = s;
    }
  }
}

// ---------------------------------------------------------------------------
// k_fused: per layer, one wave per node n:
//   agg = mean over in-neighbors of xin[src]          (gather, 16-deep MLP)
//   xout[n] = relu(agg @ Wl^T + bl + xin[n] @ Wr^T)   (shuffle-broadcast GEMM)
// xin != xout (ping-pong buffers) -> no in-place hazard.
// Weights staged interleaved in LDS: WS[k*64+j] = {Wl[j][k], Wr[j][k]}.
// The update FMAs execute in other waves' gather-stall shadows.
// ---------------------------------------------------------------------------
__global__ __launch_bounds__(256) void k_fused(
    const int* __restrict__ rowptr, const int* __restrict__ col,
    const float* __restrict__ xin,
    const float* __restrict__ Wl, const float* __restrict__ bl,
    const float* __restrict__ Wr, float* __restrict__ xout) {
  __shared__ float2 WS[HID * HID];   // 32 KB
  int t = threadIdx.x;
  for (int idx = t; idx < HID * HID; idx += 256) {
    int k = idx & 63, j = idx >> 6;               // k consecutive -> coalesced
    WS[k * HID + j] = make_float2(Wl[j * HID + k], Wr[j * HID + k]);
  }
  __syncthreads();

  int lane = t & 63;
  int wv = t >> 6;
  int n = blockIdx.x * 4 + wv;
  int rp0 = rowptr[n], rp1 = rowptr[n + 1];
  int r = lane >> 4;          // neighbor slot 0..3
  int c = lane & 15;          // float4 column 0..15
  const float4* x4 = (const float4*)xin;

  float4 a0 = {0.f, 0.f, 0.f, 0.f};
  float4 a1 = {0.f, 0.f, 0.f, 0.f};
  float4 a2 = {0.f, 0.f, 0.f, 0.f};
  float4 a3 = {0.f, 0.f, 0.f, 0.f};
  int base = rp0;
  for (; base + 16 <= rp1; base += 16) {
    int s0 = col[base + r];
    int s1 = col[base + 4 + r];
    int s2 = col[base + 8 + r];
    int s3 = col[base + 12 + r];
    float4 v0 = x4[(size_t)s0 * 16 + c];
    float4 v1 = x4[(size_t)s1 * 16 + c];
    float4 v2 = x4[(size_t)s2 * 16 + c];
    float4 v3 = x4[(size_t)s3 * 16 + c];
    a0.x += v0.x; a0.y += v0.y; a0.z += v0.z; a0.w += v0.w;
    a1.x += v1.x; a1.y += v1.y; a1.z += v1.z; a1.w += v1.w;
    a2.x += v2.x; a2.y += v2.y; a2.z += v2.z; a2.w += v2.w;
    a3.x += v3.x; a3.y += v3.y; a3.z += v3.z; a3.w += v3.w;
  }
  if (base + 4 <= rp1) {
    int s0 = col[base + r];
    float4 v0 = x4[(size_t)s0 * 16 + c];
    a0.x += v0.x; a0.y += v0.y; a0.z += v0.z; a0.w += v0.w;
    base += 4;
  }
  if (base + 4 <= rp1) {
    int s1 = col[base + r];
    float4 v1 = x4[(size_t)s1 * 16 + c];
    a1.x += v1.x; a1.y += v1.y; a1.z += v1.z; a1.w += v1.w;
    base += 4;
  }
  if (base + 4 <= rp1) {
    int s2 = col[base + r];
    float4 v2 = x4[(size_t)s2 * 16 + c];
    a2.x += v2.x; a2.y += v2.y; a2.z += v2.z; a2.w += v2.w;
    base += 4;
  }
  if (base + r < rp1) {
    int s3 = col[base + r];
    float4 v3 = x4[(size_t)s3 * 16 + c];
    a3.x += v3.x; a3.y += v3.y; a3.z += v3.z; a3.w += v3.w;
  }
  float4 a;
  a.x = (a0.x + a1.x) + (a2.x + a3.x);
  a.y = (a0.y + a1.y) + (a2.y + a3.y);
  a.z = (a0.z + a1.z) + (a2.z + a3.z);
  a.w = (a0.w + a1.w) + (a2.w + a3.w);
  a.x += __shfl_xor(a.x, 16); a.y += __shfl_xor(a.y, 16);
  a.z += __shfl_xor(a.z, 16); a.w += __shfl_xor(a.w, 16);
  a.x += __shfl_xor(a.x, 32); a.y += __shfl_xor(a.y, 32);
  a.z += __shfl_xor(a.z, 32); a.w += __shfl_xor(a.w, 32);
  // all lanes now hold neighbor-sum features 4c..4c+3; apply mean
  float id = 1.0f / (float)max(rp1 - rp0, 1);
  a.x *= id; a.y *= id; a.z *= id; a.w *= id;
  // own row (features 4c..4c+3)
  float4 xv = x4[(size_t)n * 16 + c];

  // dual matmul: lane = output feature j; broadcast k-features via shuffles
  float accA = 0.f, accX = 0.f;
#pragma unroll
  for (int cc = 0; cc < 16; ++cc) {
    float4 am, xm;
    am.x = __shfl(a.x, cc);  am.y = __shfl(a.y, cc);
    am.z = __shfl(a.z, cc);  am.w = __shfl(a.w, cc);
    xm.x = __shfl(xv.x, cc); xm.y = __shfl(xv.y, cc);
    xm.z = __shfl(xv.z, cc); xm.w = __shfl(xv.w, cc);
    float2 w0 = WS[(4 * cc + 0) * HID + lane];
    float2 w1 = WS[(4 * cc + 1) * HID + lane];
    float2 w2 = WS[(4 * cc + 2) * HID + lane];
    float2 w3 = WS[(4 * cc + 3) * HID + lane];
    accA += am.x * w0.x + am.y * w1.x + am.z * w2.x + am.w * w3.x;
    accX += xm.x * w0.y + xm.y * w1.y + xm.z * w2.y + xm.w * w3.y;
  }
  float v = accA + accX + bl[lane];
  xout[(size_t)n * HID + lane] = fmaxf(v, 0.f);
}

// ---------------------------------------------------------------------------
extern "C" void kernel_launch(void* const* d_in, const int* in_sizes, int n_in,
                              void* d_out, int out_size, void* d_ws, size_t ws_size,
                              hipStream_t stream) {
  const float* track_x  = (const float*)d_in[0];
  const int*   pl_tr_s  = (const int*)d_in[1];
  const int*   pl_tr_d  = (const int*)d_in[2];
  const int*   tr_ar_s  = (const int*)d_in[3];
  const int*   tr_ar_d  = (const int*)d_in[4];
  const float* pl_emb   = (const float*)d_in[5];
  const float* ar_emb   = (const float*)d_in[6];
  const float* track_W  = (const float*)d_in[7];
  const float* track_b  = (const float*)d_in[8];
  const float* type_emb = (const float*)d_in[9];
  const float* conv_Wl  = (const float*)d_in[10];
  const float* conv_bl  = (const float*)d_in[11];
  const float* conv_Wr  = (const float*)d_in[12];

  float* x = (float*)d_out;                      // node state (NN*64)

  // workspace layout (identical structure to R7's passing run)
  char* w = (char*)d_ws;
  float* xb     = (float*)w;                     w += (size_t)NN * HID * 4;
  int*   degi   = (int*)w;                       w += (size_t)NN * 4;
  int*   rowptr = (int*)w;                       w += (size_t)(NN + 1) * 4;
  int*   cursor = (int*)w;                       w += (size_t)(NN + 1) * 4;
  int*   bsum   = (int*)w;                       w += (size_t)1024 * 4;
  int*   col    = (int*)w;                       // E_TOT ints

  hipMemsetAsync(degi, 0, NN * sizeof(int), stream);

  k_init_emb<<<(NUM_PL + NUM_AR) * HID / 256, 256, 0, stream>>>(
      pl_emb, ar_emb, type_emb, x);
  k_track_lin<<<NUM_TR / 32, 256, 0, stream>>>(
      track_x, track_W, track_b, type_emb, x);

  // CSR build
  k_deg_int<<<(E_TOT + 255) / 256, 256, 0, stream>>>(
      pl_tr_s, pl_tr_d, tr_ar_s, tr_ar_d, degi);
  k_scan1<<<NBLK_SCAN, 256, 0, stream>>>(degi, rowptr, bsum);
  k_scan2<<<1, 1024, 0, stream>>>(bsum);
  k_scan3<<<NBLK_SCAN, 256, 0, stream>>>(rowptr, bsum, cursor);
  k_fill<<<FILL_CHUNKS * 8, 256, 0, stream>>>(
      pl_tr_s, pl_tr_d, tr_ar_s, tr_ar_d, cursor, col);

  // layer 0: x -> xb ; layer 1: xb -> x  (ping-pong, no in-place hazard)
  k_fused<<<NN / 4, 256, 0, stream>>>(
      rowptr, col, x, conv_Wl, conv_bl, conv_Wr, xb);
  k_fused<<<NN / 4, 256, 0, stream>>>(
      rowptr, col, xb, conv_Wl + HID * HID, conv_bl + HID,
      conv_Wr + HID * HID, x);
}

// Round 9
// 998.530 us; speedup vs baseline: 1.7332x; 1.7332x over previous
//
#include <hip/hip_runtime.h>

#define NUM_PL 50000
#define NUM_TR 100000
#define NUM_AR 10000
#define NN     160000          // NUM_PL + NUM_TR + NUM_AR
#define HID    64
#define FEAT   128
#define E_PLTR 2000000
#define E_TRAR 100000
#define E_TOT  4200000         // 2*E_PLTR + 2*E_TRAR
#define OFF_TR 50000
#define OFF_AR 150000
#define NBLK_SCAN 625          // NN / 256

#define BIN_CHUNK 8192
#define NBLK_BIN  513          // ceil(E_TOT / BIN_CHUNK)
#define NBUCK     625          // NN / 256 (exact)
#define TABW      626          // NBUCK + 1
#define PKD_CAP   (NBLK_BIN * BIN_CHUNK)

// edge id -> (src,dst) global node ids, matching the reference concatenation
__device__ __forceinline__ void edge_sd(
    int e, const int* __restrict__ pls, const int* __restrict__ pld,
    const int* __restrict__ tas, const int* __restrict__ tad, int& s, int& d) {
  if (e < E_PLTR)                   { s = pls[e];               d = pld[e] + OFF_TR; }
  else if (e < 2 * E_PLTR)          { int i = e - E_PLTR;
                                      s = pld[i] + OFF_TR;      d = pls[i]; }
  else if (e < 2 * E_PLTR + E_TRAR) { int i = e - 2 * E_PLTR;
                                      s = tas[i] + OFF_TR;      d = tad[i] + OFF_AR; }
  else                              { int i = e - 2 * E_PLTR - E_TRAR;
                                      s = tad[i] + OFF_AR;      d = tas[i] + OFF_TR; }
}

// ---------------------------------------------------------------------------
// x[pl] = playlist_emb + type_emb[0];  x[ar] = artist_emb + type_emb[2]
// ---------------------------------------------------------------------------
__global__ __launch_bounds__(256) void k_init_emb(
    const float* __restrict__ pl_emb, const float* __restrict__ ar_emb,
    const float* __restrict__ type_emb, float* __restrict__ x) {
  int tid = blockIdx.x * 256 + threadIdx.x;
  int f = tid & (HID - 1);
  if (tid < NUM_PL * HID) {
    x[tid] = pl_emb[tid] + type_emb[f];
  } else {
    int idx = tid - NUM_PL * HID;
    if (idx < NUM_AR * HID)
      x[OFF_AR * HID + idx] = ar_emb[idx] + type_emb[2 * HID + f];
  }
}

// ---------------------------------------------------------------------------
// x[tr] = track_x @ W^T + b + type_emb[1]   (wave: 8 rows, lane = out feat)
// ---------------------------------------------------------------------------
__global__ __launch_bounds__(256) void k_track_lin(
    const float* __restrict__ tx, const float* __restrict__ W,
    const float* __restrict__ b, const float* __restrict__ type_emb,
    float* __restrict__ x) {
  __shared__ float WS[FEAT * HID];   // WS[k*64 + j] = W[j*128 + k]
  __shared__ float bs[HID];
  int t = threadIdx.x;
  for (int idx = t; idx < HID * FEAT; idx += 256) {
    int j = idx >> 7, k = idx & (FEAT - 1);
    WS[k * HID + j] = W[idx];
  }
  if (t < HID) bs[t] = b[t] + type_emb[HID + t];
  __syncthreads();

  int j  = t & 63;
  int wv = __builtin_amdgcn_readfirstlane(t >> 6);
  int row0 = blockIdx.x * 32 + wv * 8;
  const float* xr = tx + (size_t)row0 * FEAT;

  float acc[8] = {0.f, 0.f, 0.f, 0.f, 0.f, 0.f, 0.f, 0.f};
#pragma unroll 4
  for (int k = 0; k < FEAT; ++k) {
    float w = WS[k * HID + j];
#pragma unroll
    for (int r = 0; r < 8; ++r)
      acc[r] += xr[r * FEAT + k] * w;
  }
#pragma unroll
  for (int r = 0; r < 8; ++r)
    x[(OFF_TR + row0 + r) * HID + j] = acc[r] + bs[j];
}

// ---------------------------------------------------------------------------
// CSR build: int degree count
// ---------------------------------------------------------------------------
__global__ __launch_bounds__(256) void k_deg_int(
    const int* __restrict__ pls, const int* __restrict__ pld,
    const int* __restrict__ tas, const int* __restrict__ tad,
    int* __restrict__ degi) {
  int e = blockIdx.x * 256 + threadIdx.x;
  if (e >= E_TOT) return;
  int s, d;
  edge_sd(e, pls, pld, tas, tad, s, d);
  atomicAdd(&degi[d], 1);
}

// ---------------------------------------------------------------------------
// scan1: per-block (256) exclusive scan of degi -> rowptr, block total -> bsum
// ---------------------------------------------------------------------------
__global__ __launch_bounds__(256) void k_scan1(
    const int* __restrict__ degi, int* __restrict__ rowptr,
    int* __restrict__ bsum) {
  __shared__ int s[256];
  int t = threadIdx.x;
  int i = blockIdx.x * 256 + t;
  int val = degi[i];
  s[t] = val;
  __syncthreads();
  int incl = val;
#pragma unroll
  for (int off = 1; off < 256; off <<= 1) {
    int add = (t >= off) ? s[t - off] : 0;
    __syncthreads();
    incl += add;
    s[t] = incl;
    __syncthreads();
  }
  rowptr[i] = incl - val;               // exclusive within block
  if (t == 255) bsum[blockIdx.x] = incl;
}

// ---------------------------------------------------------------------------
// scan2: single block (1024 threads) exclusive scan of the 625 block sums
// ---------------------------------------------------------------------------
__global__ __launch_bounds__(1024) void k_scan2(int* __restrict__ bsum) {
  __shared__ int s[1024];
  int t = threadIdx.x;
  int val = (t < NBLK_SCAN) ? bsum[t] : 0;
  s[t] = val;
  __syncthreads();
  int incl = val;
#pragma unroll
  for (int off = 1; off < 1024; off <<= 1) {
    int add = (t >= off) ? s[t - off] : 0;
    __syncthreads();
    incl += add;
    s[t] = incl;
    __syncthreads();
  }
  if (t < NBLK_SCAN) bsum[t] = incl - val;  // exclusive
}

// ---------------------------------------------------------------------------
// scan3: rowptr[i] += bsum[block]; rowptr[NN]=E_TOT
// ---------------------------------------------------------------------------
__global__ __launch_bounds__(256) void k_scan3(
    int* __restrict__ rowptr, const int* __restrict__ bsum) {
  int i = blockIdx.x * 256 + threadIdx.x;
  rowptr[i] += bsum[blockIdx.x];
  if (i == 0) rowptr[NN] = E_TOT;
}

// ---------------------------------------------------------------------------
// k_bin: each block takes BIN_CHUNK edges, groups them by dst bucket (d>>8)
// inside LDS, writes packed entries (d_off<<18 | s) to its OWN contiguous
// region pkd[e0 .. e0+cnt) -- dense block-private writes, zero cross-XCD
// line sharing. tab[blk*TABW + b] = absolute slice start.
// All derived indices clamped: worst case = wrong data, never OOB.
// ---------------------------------------------------------------------------
__global__ __launch_bounds__(256) void k_bin(
    const int* __restrict__ pls, const int* __restrict__ pld,
    const int* __restrict__ tas, const int* __restrict__ tad,
    int* __restrict__ pkd, int* __restrict__ tab) {
  __shared__ int hist[TABW];     // counts, then reused as write cursors
  __shared__ int offs[TABW];     // exclusive scan
  __shared__ int scanbuf[256];
  int t = threadIdx.x;
  int blk = blockIdx.x;
  int e0 = blk * BIN_CHUNK;
  int e1 = e0 + BIN_CHUNK; if (e1 > E_TOT) e1 = E_TOT;

  for (int i = t; i < TABW; i += 256) hist[i] = 0;
  __syncthreads();

  for (int e = e0 + t; e < e1; e += 256) {
    int s, d; edge_sd(e, pls, pld, tas, tad, s, d);
    int b = min(max(d >> 8, 0), NBUCK - 1);
    atomicAdd(&hist[b], 1);
  }
  __syncthreads();

  // exclusive scan of hist[0..624] -> offs[0..625]
  int i0 = 3 * t, i1 = 3 * t + 1, i2 = 3 * t + 2;
  int h0 = (i0 < NBUCK) ? hist[i0] : 0;
  int h1 = (i1 < NBUCK) ? hist[i1] : 0;
  int h2 = (i2 < NBUCK) ? hist[i2] : 0;
  int lsum = h0 + h1 + h2;
  scanbuf[t] = lsum;
  __syncthreads();
  int incl = lsum;
#pragma unroll
  for (int off = 1; off < 256; off <<= 1) {
    int add = (t >= off) ? scanbuf[t - off] : 0;
    __syncthreads();
    incl += add;
    scanbuf[t] = incl;
    __syncthreads();
  }
  int base = incl - lsum;
  if (i0 < TABW) offs[i0] = base;
  if (i1 < TABW) offs[i1] = base + h0;
  if (i2 < TABW) offs[i2] = base + h0 + h1;
  __syncthreads();

  for (int i = t; i < TABW; i += 256) tab[blk * TABW + i] = e0 + offs[i];
  for (int i = t; i < NBUCK; i += 256) hist[i] = offs[i];  // cursors
  __syncthreads();

  for (int e = e0 + t; e < e1; e += 256) {
    int s, d; edge_sd(e, pls, pld, tas, tad, s, d);
    int b = min(max(d >> 8, 0), NBUCK - 1);
    int pos = atomicAdd(&hist[b], 1);
    int idx = min(max(e0 + pos, 0), PKD_CAP - 1);   // clamp (no-op if correct)
    pkd[idx] = ((d & 255) << 18) | s;
  }
}

// ---------------------------------------------------------------------------
// k_fill2: one WG per 256-node bucket; walks its 513 pkd slices and writes
// col densely into the bucket's contiguous CSR window [rowptr[b*256],
// rowptr[(b+1)*256]) via LDS cursors. No cross-WG write sharing.
// All derived indices clamped.
// ---------------------------------------------------------------------------
__global__ __launch_bounds__(256) void k_fill2(
    const int* __restrict__ tab, const int* __restrict__ pkd,
    const int* __restrict__ rowptr, int* __restrict__ col) {
  __shared__ int cur[256];
  int t = threadIdx.x;
  int b = blockIdx.x;
  cur[t] = rowptr[(b << 8) + t];
  __syncthreads();
  for (int blk = t; blk < NBLK_BIN; blk += 256) {
    int s0 = tab[blk * TABW + b];
    int s1 = tab[blk * TABW + b + 1];
    s0 = min(max(s0, 0), PKD_CAP);
    s1 = min(max(s1, s0), PKD_CAP);
    for (int i = s0; i < s1; ++i) {
      int pk = pkd[i];
      int doff = (pk >> 18) & 255;
      int pos = atomicAdd(&cur[doff], 1);
      pos = min(max(pos, 0), E_TOT - 1);            // clamp (no-op if correct)
      col[pos] = pk & 0x3FFFF;
    }
  }
}

// ---------------------------------------------------------------------------
// gather: agg[n] = (1/deg) * sum over in-neighbors of x[src]
// one wave per node; lane = (slot r = lane>>4, float4 col c = lane&15);
// 16 edges per wave-iter -> 4 independent float4 loads in flight per lane.
// ---------------------------------------------------------------------------
__global__ __launch_bounds__(256) void k_gather(
    const int* __restrict__ rowptr, const int* __restrict__ col,
    const float* __restrict__ x, float* __restrict__ agg) {
  int t = threadIdx.x;
  int lane = t & 63;
  int wv = t >> 6;
  int n = blockIdx.x * 4 + wv;
  int rp0 = rowptr[n], rp1 = rowptr[n + 1];
  int r = lane >> 4;          // neighbor slot 0..3
  int c = lane & 15;          // float4 column 0..15
  const float4* x4 = (const float4*)x;

  float4 a0 = {0.f, 0.f, 0.f, 0.f};
  float4 a1 = {0.f, 0.f, 0.f, 0.f};
  float4 a2 = {0.f, 0.f, 0.f, 0.f};
  float4 a3 = {0.f, 0.f, 0.f, 0.f};
  int base = rp0;
  for (; base + 16 <= rp1; base += 16) {
    int s0 = col[base + r];
    int s1 = col[base + 4 + r];
    int s2 = col[base + 8 + r];
    int s3 = col[base + 12 + r];
    float4 v0 = x4[(size_t)s0 * 16 + c];
    float4 v1 = x4[(size_t)s1 * 16 + c];
    float4 v2 = x4[(size_t)s2 * 16 + c];
    float4 v3 = x4[(size_t)s3 * 16 + c];
    a0.x += v0.x; a0.y += v0.y; a0.z += v0.z; a0.w += v0.w;
    a1.x += v1.x; a1.y += v1.y; a1.z += v1.z; a1.w += v1.w;
    a2.x += v2.x; a2.y += v2.y; a2.z += v2.z; a2.w += v2.w;
    a3.x += v3.x; a3.y += v3.y; a3.z += v3.z; a3.w += v3.w;
  }
  if (base + 4 <= rp1) {
    int s0 = col[base + r];
    float4 v0 = x4[(size_t)s0 * 16 + c];
    a0.x += v0.x; a0.y += v0.y; a0.z += v0.z; a0.w += v0.w;
    base += 4;
  }
  if (base + 4 <= rp1) {
    int s1 = col[base + r];
    float4 v1 = x4[(size_t)s1 * 16 + c];
    a1.x += v1.x; a1.y += v1.y; a1.z += v1.z; a1.w += v1.w;
    base += 4;
  }
  if (base + 4 <= rp1) {
    int s2 = col[base + r];
    float4 v2 = x4[(size_t)s2 * 16 + c];
    a2.x += v2.x; a2.y += v2.y; a2.z += v2.z; a2.w += v2.w;
    base += 4;
  }
  if (base + r < rp1) {
    int s3 = col[base + r];
    float4 v3 = x4[(size_t)s3 * 16 + c];
    a3.x += v3.x; a3.y += v3.y; a3.z += v3.z; a3.w += v3.w;
  }
  float4 a;
  a.x = (a0.x + a1.x) + (a2.x + a3.x);
  a.y = (a0.y + a1.y) + (a2.y + a3.y);
  a.z = (a0.z + a1.z) + (a2.z + a3.z);
  a.w = (a0.w + a1.w) + (a2.w + a3.w);
  a.x += __shfl_xor(a.x, 16); a.y += __shfl_xor(a.y, 16);
  a.z += __shfl_xor(a.z, 16); a.w += __shfl_xor(a.w, 16);
  a.x += __shfl_xor(a.x, 32); a.y += __shfl_xor(a.y, 32);
  a.z += __shfl_xor(a.z, 32); a.w += __shfl_xor(a.w, 32);
  if (r == 0) {
    float id = 1.0f / (float)max(rp1 - rp0, 1);
    float4 o;
    o.x = a.x * id; o.y = a.y * id; o.z = a.z * id; o.w = a.w * id;
    ((float4*)agg)[(size_t)n * 16 + c] = o;
  }
}

// ---------------------------------------------------------------------------
// x = relu(agg @ Wl^T + bl + x @ Wr^T)   (agg already mean'd); in-place x
// ---------------------------------------------------------------------------
__global__ __launch_bounds__(256) void k_update(
    const float* __restrict__ agg,
    const float* __restrict__ Wl, const float* __restrict__ bl,
    const float* __restrict__ Wr, float* x) {
  __shared__ float WlS[HID * HID];   // [k][j]
  __shared__ float WrS[HID * HID];
  __shared__ float bs[HID];
  int t = threadIdx.x;
  for (int idx = t; idx < HID * HID; idx += 256) {
    int j = idx >> 6, k = idx & 63;
    WlS[k * HID + j] = Wl[idx];
    WrS[k * HID + j] = Wr[idx];
  }
  if (t < HID) bs[t] = bl[t];
  __syncthreads();

  int j  = t & 63;
  int wv = __builtin_amdgcn_readfirstlane(t >> 6);
  int n0 = blockIdx.x * 32 + wv * 8;
  const float* ar = agg + (size_t)n0 * HID;
  const float* xr = x + (size_t)n0 * HID;

  float accA[8] = {0.f, 0.f, 0.f, 0.f, 0.f, 0.f, 0.f, 0.f};
  float accX[8] = {0.f, 0.f, 0.f, 0.f, 0.f, 0.f, 0.f, 0.f};
#pragma unroll 4
  for (int k = 0; k < HID; ++k) {
    float wl = WlS[k * HID + j];
    float wr = WrS[k * HID + j];
#pragma unroll
    for (int r = 0; r < 8; ++r) {
      accA[r] += ar[r * HID + k] * wl;
      accX[r] += xr[r * HID + k] * wr;
    }
  }
#pragma unroll
  for (int r = 0; r < 8; ++r) {
    float v = accA[r] + accX[r] + bs[j];
    x[(n0 + r) * HID + j] = fmaxf(v, 0.f);
  }
}

// ---------------------------------------------------------------------------
extern "C" void kernel_launch(void* const* d_in, const int* in_sizes, int n_in,
                              void* d_out, int out_size, void* d_ws, size_t ws_size,
                              hipStream_t stream) {
  const float* track_x  = (const float*)d_in[0];
  const int*   pl_tr_s  = (const int*)d_in[1];
  const int*   pl_tr_d  = (const int*)d_in[2];
  const int*   tr_ar_s  = (const int*)d_in[3];
  const int*   tr_ar_d  = (const int*)d_in[4];
  const float* pl_emb   = (const float*)d_in[5];
  const float* ar_emb   = (const float*)d_in[6];
  const float* track_W  = (const float*)d_in[7];
  const float* track_b  = (const float*)d_in[8];
  const float* type_emb = (const float*)d_in[9];
  const float* conv_Wl  = (const float*)d_in[10];
  const float* conv_bl  = (const float*)d_in[11];
  const float* conv_Wr  = (const float*)d_in[12];

  float* x = (float*)d_out;                      // node state (NN*64)

  // workspace: agg ALIASES [pkd|tab] -- pkd/tab are dead once k_fill2 has
  // produced col; agg is first written by k_gather (stream-ordered after).
  // Total: 40.96 (agg region, covers pkd 16.8 + tab 1.29) + col 16.8 +
  // degi 0.64 + rowptr 0.64 + bsum 4KB = 59.1 MB (< R7's proven 59.8 MB).
  char* w = (char*)d_ws;
  float* agg    = (float*)w;
  int*   pkd    = (int*)w;
  int*   tab    = (int*)(w + (size_t)PKD_CAP * 4);
  w += (size_t)NN * HID * 4;
  int*   col    = (int*)w;    w += (size_t)E_TOT * 4;
  int*   degi   = (int*)w;    w += (size_t)NN * 4;
  int*   rowptr = (int*)w;    w += (size_t)(NN + 1) * 4;
  int*   bsum   = (int*)w;    // 1024 ints

  hipMemsetAsync(degi, 0, NN * sizeof(int), stream);

  k_init_emb<<<(NUM_PL + NUM_AR) * HID / 256, 256, 0, stream>>>(
      pl_emb, ar_emb, type_emb, x);
  k_track_lin<<<NUM_TR / 32, 256, 0, stream>>>(
      track_x, track_W, track_b, type_emb, x);

  // CSR build: degree/scan for rowptr, then dense two-phase fill
  k_deg_int<<<(E_TOT + 255) / 256, 256, 0, stream>>>(
      pl_tr_s, pl_tr_d, tr_ar_s, tr_ar_d, degi);
  k_scan1<<<NBLK_SCAN, 256, 0, stream>>>(degi, rowptr, bsum);
  k_scan2<<<1, 1024, 0, stream>>>(bsum);
  k_scan3<<<NBLK_SCAN, 256, 0, stream>>>(rowptr, bsum);
  k_bin<<<NBLK_BIN, 256, 0, stream>>>(
      pl_tr_s, pl_tr_d, tr_ar_s, tr_ar_d, pkd, tab);
  k_fill2<<<NBUCK, 256, 0, stream>>>(tab, pkd, rowptr, col);

  for (int l = 0; l < 2; ++l) {
    k_gather<<<NN / 4, 256, 0, stream>>>(rowptr, col, x, agg);
    k_update<<<NN / 32, 256, 0, stream>>>(
        agg, conv_Wl + l * HID * HID, conv_bl + l * HID,
        conv_Wr + l * HID * HID, x);
  }
}